// Round 2
// baseline (894.933 us; speedup 1.0000x reference)
//
#include <hip/hip_runtime.h>
#include <hip/hip_bf16.h>
#include <stdint.h>

// Shapes: N=32, CIN=COUT=64, T=256, V=25, K=3, G=8, D=K*COUT=192
// All tensor inputs fp32 (per reference); compute fp32; output fp32.
// Intermediate y stored bf16 in workspace (error << threshold, halves BW).

typedef const float* fp;

__device__ __forceinline__ float us2f(unsigned int u){
  union { unsigned int i; float f; } c; c.i = u << 16; return c.f;
}

// ---------------- workspace layout (bytes) ----------------
// normA  fp32 [3][8][25][28]      @ 0        (67200 B)
// Weff   fp32 [64][192]           @ 67584    (49152 B)
// beff   fp32 [192]               @ 116736   (768 B)
// cwe    fp32 [64][64][12]        @ 117504   (196608 B)
// cbe    fp32 [64]                @ 314112   (256 B)
// y      bf16 [32][64][256][25]   @ 314368   (26214400 B)

// ---------------- precompute: fold BNs, normalize adjacency ----------------
__global__ __launch_bounds__(256) void k_pre(
    fp A, fp W, fp b, fp g0, fp b0, fp cw, fp cb, fp g2, fp b2,
    float* normA, float* Weff, float* beff, float* cwe, float* cbe)
{
  int gid = blockIdx.x * 256 + threadIdx.x;
  const float inv_s = rsqrtf(1.0f + 1e-5f);

  if (gid < 3*8*25*28) {                  // normA[k][g][v][w-pad28]
    int k  = gid / (8*25*28);
    int r  = gid % (8*25*28);
    int g  = r / (25*28);
    int r2 = r % (25*28);
    int v  = r2 / 28, w = r2 % 28;
    float val = 0.f;
    if (w < 25) {
      float s = 0.f;
      for (int vv = 0; vv < 25; vv++) s += A[((k*8+g)*25+vv)*25 + w];
      float inv = 1.0f / (s + 0.001f);
      val = A[((k*8+g)*25+v)*25 + w] * inv;
    }
    normA[gid] = val;
    return;
  }
  gid -= 3*8*25*28;
  if (gid < 64*192) {                     // Weff[c][d] = W*s0
    int d = gid % 192;
    Weff[gid] = W[gid] * (g0[d] * inv_s);
    return;
  }
  gid -= 64*192;
  if (gid < 192) {                        // beff[d] = b*s0 + b0
    float s0 = g0[gid] * inv_s;
    beff[gid] = b[gid] * s0 + b0[gid];
    return;
  }
  gid -= 192;
  if (gid < 64*64*12) {                   // cwe[o][i][j-pad12] = conv_w*s2
    int o = gid / (64*12);
    int r = gid % (64*12);
    int i = r / 12, j = r % 12;
    float s2 = g2[o] * inv_s;
    cwe[gid] = (j < 9) ? cw[(o*64+i)*9 + j] * s2 : 0.f;
    return;
  }
  gid -= 64*64*12;
  if (gid < 64) {                         // cbe[o] = cb*s2 + b2
    float s2 = g2[gid] * inv_s;
    cbe[gid] = cb[gid] * s2 + b2[gid];
  }
}

// ---------------- fused GCN: 1x1 conv + BN0 + adjacency + BN1 + res ReLU ----
__global__ __launch_bounds__(256) void k_gcn(
    fp x, const float* Weff, const float* beff, const float* normA,
    fp g1, fp b1, __hip_bfloat16* y)
{
  int n = blockIdx.x >> 8, t = blockIdx.x & 255, tid = threadIdx.x;
  __shared__ float xs[64*28];    // x[n,:,t,:], rows padded 25->28 for float4
  __shared__ float y1s[192*25];  // stage-1 output

  for (int e = tid; e < 1600; e += 256) {
    int c = e / 25, v = e - c*25;
    xs[c*28 + v] = x[((n*64+c)*256 + t)*25 + v];
  }
  __syncthreads();

  // stage 1: y1[d,v] = beff[d] + sum_c xs[c,v] * Weff[c,d]
  if (tid < 192) {
    int d = tid;
    float acc[25];
    float be = beff[d];
    #pragma unroll
    for (int v = 0; v < 25; v++) acc[v] = be;
    #pragma unroll 4
    for (int ci = 0; ci < 64; ci++) {
      float wv = Weff[ci*192 + d];
      const float4* xr = (const float4*)(xs + ci*28);  // wave-uniform -> LDS broadcast
      float4 a0 = xr[0], a1 = xr[1], a2 = xr[2], a3 = xr[3], a4 = xr[4], a5 = xr[5];
      float x24 = xs[ci*28 + 24];
      acc[0]  += a0.x*wv; acc[1]  += a0.y*wv; acc[2]  += a0.z*wv; acc[3]  += a0.w*wv;
      acc[4]  += a1.x*wv; acc[5]  += a1.y*wv; acc[6]  += a1.z*wv; acc[7]  += a1.w*wv;
      acc[8]  += a2.x*wv; acc[9]  += a2.y*wv; acc[10] += a2.z*wv; acc[11] += a2.w*wv;
      acc[12] += a3.x*wv; acc[13] += a3.y*wv; acc[14] += a3.z*wv; acc[15] += a3.w*wv;
      acc[16] += a4.x*wv; acc[17] += a4.y*wv; acc[18] += a4.z*wv; acc[19] += a4.w*wv;
      acc[20] += a5.x*wv; acc[21] += a5.y*wv; acc[22] += a5.z*wv; acc[23] += a5.w*wv;
      acc[24] += x24*wv;
    }
    #pragma unroll
    for (int v = 0; v < 25; v++) y1s[d*25 + v] = acc[v];
  }
  __syncthreads();

  // stage 2: y2[c,w] = sum_k sum_v y1[k*64+c, v] * normA[k, c%8, v, w]
  {
    int c = tid & 63, wq = tid >> 6;
    int w0 = wq * 8;                 // wq==3 -> w0=24 (single column)
    int g = c & 7;
    float acc[8];
    #pragma unroll
    for (int i = 0; i < 8; i++) acc[i] = 0.f;

    if (wq < 3) {
      for (int k = 0; k < 3; k++) {
        const float* yb = y1s + (k*64 + c)*25;
        const float* ab = normA + (k*8 + g)*25*28 + w0;
        #pragma unroll 5
        for (int v = 0; v < 25; v++) {
          float yv = yb[v];
          const float4* ar = (const float4*)(ab + v*28);
          float4 n0 = ar[0], n1 = ar[1];
          acc[0] += yv*n0.x; acc[1] += yv*n0.y; acc[2] += yv*n0.z; acc[3] += yv*n0.w;
          acc[4] += yv*n1.x; acc[5] += yv*n1.y; acc[6] += yv*n1.z; acc[7] += yv*n1.w;
        }
      }
    } else {
      for (int k = 0; k < 3; k++) {
        const float* yb = y1s + (k*64 + c)*25;
        const float* ab = normA + (k*8 + g)*25*28 + 24;
        #pragma unroll 5
        for (int v = 0; v < 25; v++) acc[0] += yb[v] * ab[v*28];
      }
    }

    float s1 = g1[c] * rsqrtf(1.0f + 1e-5f);
    float bb = b1[c];
    int nw = (wq < 3) ? 8 : 1;
    for (int ww = 0; ww < nw; ww++) {
      int w = w0 + ww;
      float val = acc[ww]*s1 + bb + xs[c*28 + w];
      val = fmaxf(val, 0.f);
      y[((n*64+c)*256 + t)*25 + w] = __float2bfloat16(val);
    }
  }
}

// ---------------- TCN: 9-tap temporal conv + BN2 + residual ReLU ------------
__global__ __launch_bounds__(256) void k_tcn(
    const unsigned short* y, const float* cwe, const float* cbe, fp x,
    float* out)
{
  int n = blockIdx.x >> 5, tb = blockIdx.x & 31, tid = threadIdx.x;
  int t0 = tb * 8;
  // window y[n, i, t0-4 .. t0+11, v] as bf16, layout [i][v][tt], row stride 20
  // ushorts (40 B: 8B-aligned uint2 reads, bank-friendly stride of 10 words)
  __shared__ __align__(16) unsigned short ys[64*25*20];

  for (int e = tid; e < 25600; e += 256) {
    int i = e / 400, r = e - i*400;
    int tt = r / 25, v = r - tt*25;
    int tp = t0 - 4 + tt;
    unsigned short val = 0;
    if (tp >= 0 && tp < 256) val = y[((n*64+i)*256 + tp)*25 + v];
    ys[(i*25 + v)*20 + tt] = val;
  }
  __syncthreads();

  for (int p = tid; p < 1600; p += 256) {
    int o = p / 25, v = p - o*25;
    float cb = cbe[o];
    float acc[8];
    #pragma unroll
    for (int tl = 0; tl < 8; tl++) acc[tl] = cb;

    for (int i = 0; i < 64; i++) {
      const uint2* yr = (const uint2*)(ys + (i*25 + v)*20);
      uint2 q0 = yr[0], q1 = yr[1], q2 = yr[2], q3 = yr[3];
      float win[16];
      win[0]  = us2f(q0.x & 0xffffu); win[1]  = us2f(q0.x >> 16);
      win[2]  = us2f(q0.y & 0xffffu); win[3]  = us2f(q0.y >> 16);
      win[4]  = us2f(q1.x & 0xffffu); win[5]  = us2f(q1.x >> 16);
      win[6]  = us2f(q1.y & 0xffffu); win[7]  = us2f(q1.y >> 16);
      win[8]  = us2f(q2.x & 0xffffu); win[9]  = us2f(q2.x >> 16);
      win[10] = us2f(q2.y & 0xffffu); win[11] = us2f(q2.y >> 16);
      win[12] = us2f(q3.x & 0xffffu); win[13] = us2f(q3.x >> 16);
      win[14] = us2f(q3.y & 0xffffu); win[15] = us2f(q3.y >> 16);

      const float4* cwr = (const float4*)(cwe + (o*64 + i)*12);
      float4 c0 = cwr[0], c1 = cwr[1], c2 = cwr[2];
      float cw9[9] = {c0.x, c0.y, c0.z, c0.w, c1.x, c1.y, c1.z, c1.w, c2.x};
      #pragma unroll
      for (int tl = 0; tl < 8; tl++) {
        #pragma unroll
        for (int j = 0; j < 9; j++) acc[tl] += win[tl + j] * cw9[j];
      }
    }

    #pragma unroll
    for (int tl = 0; tl < 8; tl++) {
      int t = t0 + tl;
      float val = acc[tl] + x[((n*64+o)*256 + t)*25 + v];
      out[((n*64+o)*256 + t)*25 + v] = fmaxf(val, 0.f);
    }
  }
}

extern "C" void kernel_launch(void* const* d_in, const int* in_sizes, int n_in,
                              void* d_out, int out_size, void* d_ws, size_t ws_size,
                              hipStream_t stream)
{
  fp x  = (fp)d_in[0];
  fp A  = (fp)d_in[1];
  fp W  = (fp)d_in[2];
  fp b  = (fp)d_in[3];
  fp g0 = (fp)d_in[4];
  fp b0 = (fp)d_in[5];
  fp g1 = (fp)d_in[6];
  fp b1 = (fp)d_in[7];
  fp cw = (fp)d_in[8];
  fp cb = (fp)d_in[9];
  fp g2 = (fp)d_in[10];
  fp b2 = (fp)d_in[11];
  // d_in[12] = keep_prob == 1 -> DropBlocks are identity, ignored.

  char* ws = (char*)d_ws;
  float* normA = (float*)(ws + 0);
  float* Weff  = (float*)(ws + 67584);
  float* beff  = (float*)(ws + 116736);
  float* cwe   = (float*)(ws + 117504);
  float* cbe   = (float*)(ws + 314112);
  __hip_bfloat16* y = (__hip_bfloat16*)(ws + 314368);

  k_pre<<<307, 256, 0, stream>>>(A, W, b, g0, b0, cw, cb, g2, b2,
                                 normA, Weff, beff, cwe, cbe);
  k_gcn<<<32*256, 256, 0, stream>>>(x, Weff, beff, normA, g1, b1, y);
  k_tcn<<<32*32, 256, 0, stream>>>((const unsigned short*)y, cwe, cbe, x,
                                   (float*)d_out);
}

// Round 3
// 279.212 us; speedup vs baseline: 3.2052x; 3.2052x over previous
//
#include <hip/hip_runtime.h>
#include <hip/hip_bf16.h>
#include <stdint.h>

// Shapes: N=32, CIN=COUT=64, T=256, V=25, K3=3, G=8
// GCN folded to one GEMM: M=1600 (m=w*64+c), K=1600 (k=cin*25+v), N=8192 (n,t)
// TCN: MFMA im2col GEMM: M=64 (o), K=576 (i,j), N=204800 (n,t,v)

typedef const float* fp;
typedef __attribute__((ext_vector_type(8))) short short8;   // 8 bf16 (4 VGPRs)
typedef __attribute__((ext_vector_type(4))) float floatx4;  // MFMA acc

__device__ __forceinline__ float us2f(unsigned int u){
  union { unsigned int i; float f; } c; c.i = u << 16; return c.f;
}
__device__ __forceinline__ unsigned short f2us(float f){
  __hip_bfloat16 h = __float2bfloat16(f);
  return *reinterpret_cast<unsigned short*>(&h);
}

// ---------------- workspace layout (bytes) ----------------
// normA fp32 [3][8][25][28] @ 0         (67200)
// Weff  fp32 [64][192]      @ 67584     (49152)
// beff  fp32 [192]          @ 116736    (768)
// cbe   fp32 [64]           @ 117504    (256)
// cwetb bf16 [64][9][64]    @ 117760    (73728)
// biasU fp32 [1600]         @ 191488    (6400)
// U     bf16 [1664][1600]   @ 197888    (5324800)
// xb    bf16 [32][256][1600]@ 5522688   (26214400)
// yb    bf16 [32][256][1600]@ 31737088  (26214400)   total ~58 MB

// ---------------- pre 1: BN folds + adjacency normalize ----------------
__global__ __launch_bounds__(256) void k_pre(
    fp A, fp W, fp b, fp g0, fp b0, fp cw, fp cb, fp g2, fp b2,
    float* normA, float* Weff, float* beff, float* cbe, unsigned short* cwetb)
{
  int gid = blockIdx.x * 256 + threadIdx.x;
  const float inv_s = rsqrtf(1.0f + 1e-5f);

  if (gid < 16800) {                      // normA[k][g][v][w pad28]
    int k  = gid / 5600;
    int r  = gid % 5600;
    int g  = r / 700;
    int r2 = r % 700;
    int v  = r2 / 28, w = r2 % 28;
    float val = 0.f;
    if (w < 25) {
      float s = 0.f;
      for (int vv = 0; vv < 25; vv++) s += A[((k*8+g)*25+vv)*25 + w];
      val = A[((k*8+g)*25+v)*25 + w] / (s + 0.001f);
    }
    normA[gid] = val;
    return;
  }
  gid -= 16800;
  if (gid < 12288) {                      // Weff[cin][192]
    int d = gid % 192;
    Weff[gid] = W[gid] * (g0[d] * inv_s);
    return;
  }
  gid -= 12288;
  if (gid < 192) {                        // beff
    beff[gid] = b[gid] * (g0[gid] * inv_s) + b0[gid];
    return;
  }
  gid -= 192;
  if (gid < 64) {                         // cbe
    cbe[gid] = cb[gid] * (g2[gid] * inv_s) + b2[gid];
    return;
  }
  gid -= 64;
  if (gid < 36864) {                      // cwetb[o][j][i] bf16
    int o = gid / 576, r = gid % 576;
    int j = r / 64, i = r % 64;
    cwetb[gid] = f2us(cw[(o*64+i)*9 + j] * (g2[o] * inv_s));
  }
}

// ---------------- pre 2: combined GCN operator U + biasU ----------------
__global__ __launch_bounds__(256) void k_pre2(
    const float* Weff, const float* beff, const float* normA, fp g1, fp b1,
    unsigned short* U, float* biasU)
{
  const float inv_s = rsqrtf(1.0f + 1e-5f);
  long long gid = (long long)blockIdx.x * 256 + threadIdx.x;
  const long long NU = 1664LL * 1600;
  if (gid < NU) {
    int m = (int)(gid / 1600), k = (int)(gid % 1600);
    unsigned short val = 0;
    if (m < 1600) {
      int c = m & 63, w = m >> 6;
      int cin = k / 25, vv = k % 25;
      float s1 = g1[c] * inv_s;
      float acc = 0.f;
      #pragma unroll
      for (int kk = 0; kk < 3; kk++)
        acc += Weff[cin*192 + kk*64 + c] * normA[((kk*8 + (c&7))*25 + vv)*28 + w];
      val = f2us(acc * s1);
    }
    U[gid] = val;
    return;
  }
  int m = (int)(gid - NU);
  if (m < 1600) {
    int c = m & 63, w = m >> 6;
    float s1 = g1[c] * inv_s;
    float acc = 0.f;
    for (int kk = 0; kk < 3; kk++) {
      float be = beff[kk*64 + c];
      for (int v = 0; v < 25; v++)
        acc += be * normA[((kk*8 + (c&7))*25 + v)*28 + w];
    }
    biasU[m] = acc * s1 + b1[c];
  }
}

// ---------------- transpose x -> bf16 [n][t][cin*25+v] ----------------
__global__ __launch_bounds__(256) void k_xt(fp x, unsigned short* xb)
{
  int n = blockIdx.x >> 5, tb = blockIdx.x & 31, t0 = tb*8, tid = threadIdx.x;
  __shared__ unsigned short xs[64*8*26];
  for (int e = tid; e < 12800; e += 256) {
    int c = e / 200, r = e - c*200, tt = r / 25, v = r - tt*25;
    xs[(c*8 + tt)*26 + v] = f2us(x[((n*64 + c)*256 + t0 + tt)*25 + v]);
  }
  __syncthreads();
  for (int e = tid; e < 12800; e += 256) {
    int tt = e / 1600, q = e - tt*1600, c = q / 25, v = q - c*25;
    xb[(n*256 + t0 + tt)*1600 + q] = xs[(c*8 + tt)*26 + v];
  }
}

// ---------------- GCN as one MFMA GEMM + fused epilogue ----------------
// yb[n][t][m] = relu( sum_k U[m][k]*xb[n][t][k] + biasU[m] + x[n][c][t][w] )
__global__ __launch_bounds__(256) void k_gemm(
    const unsigned short* U, const unsigned short* xb, const float* biasU,
    unsigned short* yb)
{
  int bm = blockIdx.x / 64, bn = blockIdx.x % 64;
  int n = bn >> 1, t0 = (bn & 1) * 128;
  int tid = threadIdx.x, lane = tid & 63, wid = tid >> 6;
  int l15 = lane & 15, grp = lane >> 4;
  int m0w = (wid & 1) * 64, c0w = (wid >> 1) * 64;

  __shared__ __align__(16) unsigned short As[128*72];
  __shared__ __align__(16) unsigned short Bs[128*72];

  floatx4 acc[4][4];
  #pragma unroll
  for (int i = 0; i < 4; i++)
    #pragma unroll
    for (int j = 0; j < 4; j++) acc[i][j] = (floatx4){0.f,0.f,0.f,0.f};

  for (int kc = 0; kc < 25; kc++) {
    #pragma unroll
    for (int it = 0; it < 4; it++) {
      int e = tid + it*256;
      int row = e >> 3, li = e & 7;
      uint4 va = *(const uint4*)(U  + ((long long)(bm*128 + row)*1600 + kc*64 + li*8));
      uint4 vb = *(const uint4*)(xb + ((long long)(n*256 + t0 + row)*1600 + kc*64 + li*8));
      *(uint4*)(As + row*72 + li*8) = va;
      *(uint4*)(Bs + row*72 + li*8) = vb;
    }
    __syncthreads();
    #pragma unroll
    for (int ks = 0; ks < 2; ks++) {
      int ko = ks*32 + grp*8;
      short8 af[4], bf[4];
      #pragma unroll
      for (int i = 0; i < 4; i++) af[i] = *(const short8*)(As + (m0w + i*16 + l15)*72 + ko);
      #pragma unroll
      for (int j = 0; j < 4; j++) bf[j] = *(const short8*)(Bs + (c0w + j*16 + l15)*72 + ko);
      #pragma unroll
      for (int i = 0; i < 4; i++)
        #pragma unroll
        for (int j = 0; j < 4; j++)
          acc[i][j] = __builtin_amdgcn_mfma_f32_16x16x32_bf16(af[i], bf[j], acc[i][j], 0, 0, 0);
    }
    __syncthreads();
  }

  // epilogue: bias + residual + relu -> yb bf16
  #pragma unroll
  for (int i = 0; i < 4; i++) {
    int mbase = bm*128 + m0w + i*16 + grp*4;
    if (mbase >= 1600) continue;
    float4 bu = *(const float4*)(biasU + mbase);
    int c0 = mbase & 63, w = mbase >> 6;
    #pragma unroll
    for (int j = 0; j < 4; j++) {
      int col = c0w + j*16 + l15;
      int t = t0 + col;
      const unsigned short* xrow = xb + (long long)(n*256 + t)*1600;
      ushort4 pk;
      float v0 = acc[i][j][0] + bu.x + us2f(xrow[(c0+0)*25 + w]);
      float v1 = acc[i][j][1] + bu.y + us2f(xrow[(c0+1)*25 + w]);
      float v2 = acc[i][j][2] + bu.z + us2f(xrow[(c0+2)*25 + w]);
      float v3 = acc[i][j][3] + bu.w + us2f(xrow[(c0+3)*25 + w]);
      pk.x = f2us(fmaxf(v0, 0.f)); pk.y = f2us(fmaxf(v1, 0.f));
      pk.z = f2us(fmaxf(v2, 0.f)); pk.w = f2us(fmaxf(v3, 0.f));
      *(ushort4*)(yb + (long long)(n*256 + t)*1600 + mbase) = pk;
    }
  }
}

// ---------------- TCN as MFMA with im2col via LDS offsets ----------------
__global__ __launch_bounds__(256) void k_tcn(
    const unsigned short* yb, const unsigned short* cwetb, const float* cbe,
    const unsigned short* xb, float* out)
{
  int n = blockIdx.x >> 5, tb = blockIdx.x & 31, t0 = tb*8;
  int tid = threadIdx.x, lane = tid & 63, wid = tid >> 6;
  int l15 = lane & 15, grp = lane >> 4;
  __shared__ __align__(16) unsigned short ys[425*72];  // [17 t][25 v][72 i-pad]

  for (int e = tid; e < 3400; e += 256) {
    int row = e >> 3, li = e & 7;
    int rt = row / 25, v = row - rt*25;
    int tg = t0 - 4 + rt;
    uint4 val = {0u,0u,0u,0u};
    if (tg >= 0 && tg < 256)
      val = *(const uint4*)(yb + ((long long)(n*256 + tg)*1600 + v*64 + li*8));
    *(uint4*)(ys + row*72 + li*8) = val;
  }

  // A-frags: conv weights, o = o0+l15, k-dim = i
  int o0 = wid * 16;
  int o = o0 + l15;
  short8 af[9][2];
  #pragma unroll
  for (int j = 0; j < 9; j++) {
    af[j][0] = *(const short8*)(cwetb + ((o*9 + j)*64 + grp*8));
    af[j][1] = *(const short8*)(cwetb + ((o*9 + j)*64 + 32 + grp*8));
  }
  float4 cb4 = *(const float4*)(cbe + o0 + grp*4);
  __syncthreads();

  for (int tile = 0; tile < 13; tile++) {
    int colb = tile*16 + l15;
    int bbase = colb*72 + grp*8;
    floatx4 acc = (floatx4){0.f,0.f,0.f,0.f};
    #pragma unroll
    for (int j = 0; j < 9; j++) {
      short8 b0 = *(const short8*)(ys + bbase + j*1800);
      short8 b1 = *(const short8*)(ys + bbase + j*1800 + 32);
      acc = __builtin_amdgcn_mfma_f32_16x16x32_bf16(af[j][0], b0, acc, 0, 0, 0);
      acc = __builtin_amdgcn_mfma_f32_16x16x32_bf16(af[j][1], b1, acc, 0, 0, 0);
    }
    if (colb < 200) {
      int tt = colb / 25, v = colb - tt*25, t = t0 + tt;
      const unsigned short* xrow = xb + (long long)(n*256 + t)*1600;
      #pragma unroll
      for (int r = 0; r < 4; r++) {
        int oo = o0 + grp*4 + r;
        float val = acc[r] + ((const float*)&cb4)[r] + us2f(xrow[oo*25 + v]);
        out[((n*64 + oo)*256 + t)*25 + v] = fmaxf(val, 0.f);
      }
    }
  }
}

extern "C" void kernel_launch(void* const* d_in, const int* in_sizes, int n_in,
                              void* d_out, int out_size, void* d_ws, size_t ws_size,
                              hipStream_t stream)
{
  fp x  = (fp)d_in[0];
  fp A  = (fp)d_in[1];
  fp W  = (fp)d_in[2];
  fp b  = (fp)d_in[3];
  fp g0 = (fp)d_in[4];
  fp b0 = (fp)d_in[5];
  fp g1 = (fp)d_in[6];
  fp b1 = (fp)d_in[7];
  fp cw = (fp)d_in[8];
  fp cb = (fp)d_in[9];
  fp g2 = (fp)d_in[10];
  fp b2 = (fp)d_in[11];
  // d_in[12] = keep_prob == 1 -> DropBlocks identity.

  char* ws = (char*)d_ws;
  float*          normA = (float*)(ws + 0);
  float*          Weff  = (float*)(ws + 67584);
  float*          beff  = (float*)(ws + 116736);
  float*          cbe   = (float*)(ws + 117504);
  unsigned short* cwetb = (unsigned short*)(ws + 117760);
  float*          biasU = (float*)(ws + 191488);
  unsigned short* U     = (unsigned short*)(ws + 197888);
  unsigned short* xb    = (unsigned short*)(ws + 5522688);
  unsigned short* yb    = (unsigned short*)(ws + 31737088);

  k_pre<<<259, 256, 0, stream>>>(A, W, b, g0, b0, cw, cb, g2, b2,
                                 normA, Weff, beff, cbe, cwetb);
  k_pre2<<<10407, 256, 0, stream>>>(Weff, beff, normA, g1, b1, U, biasU);
  k_xt<<<1024, 256, 0, stream>>>(x, xb);
  k_gemm<<<832, 256, 0, stream>>>(U, xb, biasU, yb);
  k_tcn<<<1024, 256, 0, stream>>>(yb, cwetb, cbe, xb, (float*)d_out);
}

// Round 4
// 261.957 us; speedup vs baseline: 3.4163x; 1.0659x over previous
//
#include <hip/hip_runtime.h>
#include <hip/hip_bf16.h>
#include <stdint.h>

// Shapes: N=32, CIN=COUT=64, T=256, V=25, K3=3, G=8
// GCN folded to one GEMM: M=1600 (m=w*64+c), K=1600 (k=cin*25+v), N=8192 (n,t)
//   residual (+x) folded into U's diagonal: U[w*64+c][c*25+w] += 1
// TCN: MFMA im2col GEMM: M=64 (o), K=576 (i,j), N=204800 (n,t,v)

typedef const float* fp;
typedef __attribute__((ext_vector_type(8))) short short8;   // 8 bf16 (4 VGPRs)
typedef __attribute__((ext_vector_type(4))) float floatx4;  // MFMA acc

__device__ __forceinline__ float us2f(unsigned int u){
  union { unsigned int i; float f; } c; c.i = u << 16; return c.f;
}
__device__ __forceinline__ unsigned short f2us(float f){
  __hip_bfloat16 h = __float2bfloat16(f);
  return *reinterpret_cast<unsigned short*>(&h);
}
__device__ __forceinline__ void gload_lds16(const void* g, void* l){
  __builtin_amdgcn_global_load_lds(
      (const __attribute__((address_space(1))) void*)g,
      (__attribute__((address_space(3))) void*)l, 16, 0, 0);
}

// ---------------- workspace layout (bytes) ----------------
// normA fp32 [3][8][25][28] @ 0         (67200)
// Weff  fp32 [64][192]      @ 67584     (49152)
// beff  fp32 [192]          @ 116736    (768)
// cbe   fp32 [64]           @ 117504    (256)
// cwetb bf16 [64][9][64]    @ 117760    (73728)
// biasU fp32 [1600]         @ 191488    (6400)
// U     bf16 [1664][1600]   @ 197888    (5324800)
// xb    bf16 [32][256][1600]@ 5522688   (26214400)
// yb    bf16 [32][256][1600]@ 31737088  (26214400)   total ~58 MB

// ---------------- pre 1: BN folds + adjacency normalize ----------------
__global__ __launch_bounds__(256) void k_pre(
    fp A, fp W, fp b, fp g0, fp b0, fp cw, fp cb, fp g2, fp b2,
    float* normA, float* Weff, float* beff, float* cbe, unsigned short* cwetb)
{
  int gid = blockIdx.x * 256 + threadIdx.x;
  const float inv_s = rsqrtf(1.0f + 1e-5f);

  if (gid < 16800) {                      // normA[k][g][v][w pad28]
    int k  = gid / 5600;
    int r  = gid % 5600;
    int g  = r / 700;
    int r2 = r % 700;
    int v  = r2 / 28, w = r2 % 28;
    float val = 0.f;
    if (w < 25) {
      float s = 0.f;
      for (int vv = 0; vv < 25; vv++) s += A[((k*8+g)*25+vv)*25 + w];
      val = A[((k*8+g)*25+v)*25 + w] / (s + 0.001f);
    }
    normA[gid] = val;
    return;
  }
  gid -= 16800;
  if (gid < 12288) {                      // Weff[cin][192]
    int d = gid % 192;
    Weff[gid] = W[gid] * (g0[d] * inv_s);
    return;
  }
  gid -= 12288;
  if (gid < 192) {                        // beff
    beff[gid] = b[gid] * (g0[gid] * inv_s) + b0[gid];
    return;
  }
  gid -= 192;
  if (gid < 64) {                         // cbe
    cbe[gid] = cb[gid] * (g2[gid] * inv_s) + b2[gid];
    return;
  }
  gid -= 64;
  if (gid < 36864) {                      // cwetb[o][j][i] bf16
    int o = gid / 576, r = gid % 576;
    int j = r / 64, i = r % 64;
    cwetb[gid] = f2us(cw[(o*64+i)*9 + j] * (g2[o] * inv_s));
  }
}

// ---------------- pre 2: combined GCN operator U (+identity) + biasU --------
__global__ __launch_bounds__(256) void k_pre2(
    const float* Weff, const float* beff, const float* normA, fp g1, fp b1,
    unsigned short* U, float* biasU)
{
  const float inv_s = rsqrtf(1.0f + 1e-5f);
  long long gid = (long long)blockIdx.x * 256 + threadIdx.x;
  const long long NU = 1664LL * 1600;
  if (gid < NU) {
    int m = (int)(gid / 1600), k = (int)(gid % 1600);
    unsigned short val = 0;
    if (m < 1600) {
      int c = m & 63, w = m >> 6;
      int cin = k / 25, vv = k % 25;
      float s1 = g1[c] * inv_s;
      float acc = 0.f;
      #pragma unroll
      for (int kk = 0; kk < 3; kk++)
        acc += Weff[cin*192 + kk*64 + c] * normA[((kk*8 + (c&7))*25 + vv)*28 + w];
      acc = acc * s1;
      if (cin == c && vv == w) acc += 1.0f;   // residual folded into diagonal
      val = f2us(acc);
    }
    U[gid] = val;
    return;
  }
  int m = (int)(gid - NU);
  if (m < 1600) {
    int c = m & 63, w = m >> 6;
    float s1 = g1[c] * inv_s;
    float acc = 0.f;
    for (int kk = 0; kk < 3; kk++) {
      float be = beff[kk*64 + c];
      for (int v = 0; v < 25; v++)
        acc += be * normA[((kk*8 + (c&7))*25 + v)*28 + w];
    }
    biasU[m] = acc * s1 + b1[c];
  }
}

// ---------------- transpose x -> bf16 [n][t][cin*25+v] ----------------
__global__ __launch_bounds__(256) void k_xt(fp x, unsigned short* xb)
{
  int gid = blockIdx.x * 256 + threadIdx.x;       // 8192*800 threads
  int nt = gid / 800, r = gid - nt*800;
  int n = nt >> 8, t = nt & 255;
  int q = r * 2;
  int c0 = q / 25, v0 = q - c0*25;
  int q1 = q + 1;
  int c1 = q1 / 25, v1 = q1 - c1*25;
  float f0 = x[((n*64 + c0)*256 + t)*25 + v0];
  float f1 = x[((n*64 + c1)*256 + t)*25 + v1];
  ushort2 pk;
  pk.x = f2us(f0); pk.y = f2us(f1);
  *(ushort2*)(xb + (long long)nt*1600 + q) = pk;
}

// ---------------- GCN as one MFMA GEMM (m97 structure) ----------------
// yb[n][t][m] = relu( sum_k U[m][k]*xb[n][t][k] + biasU[m] )   (residual in U)
// LDS: unpadded [128][64] bf16; k-block column XOR-swizzled by (row&7) so
// global_load_lds deposits (wave-uniform base + lane*16) stay contiguous
// while fragment ds_read_b128s are 2-way (free).
__global__ __launch_bounds__(256) void k_gemm(
    const unsigned short* U, const unsigned short* xb, const float* biasU,
    unsigned short* yb)
{
  int bm = blockIdx.x / 64, bn = blockIdx.x % 64;
  int n = bn >> 1, t0 = (bn & 1) * 128;
  int tid = threadIdx.x, lane = tid & 63, wid = tid >> 6;
  int l15 = lane & 15, grp = lane >> 4;
  int m0w = (wid & 1) * 64, c0w = (wid >> 1) * 64;

  __shared__ __align__(16) unsigned short As[128*64];
  __shared__ __align__(16) unsigned short Bs[128*64];

  // staging geometry: round it -> e = it*256+tid, row=e>>3, li=e&7
  const unsigned short* gA[4];
  const unsigned short* gB[4];
  unsigned short* lA[4];
  unsigned short* lB[4];
  #pragma unroll
  for (int it = 0; it < 4; it++) {
    int e = it*256 + tid;
    int row = e >> 3, li = e & 7;
    int kcol = (li ^ (row & 7)) * 8;       // XOR swizzle on global source side
    gA[it] = U  + (long long)(bm*128 + row)*1600 + kcol;
    gB[it] = xb + (long long)(n*256 + t0 + row)*1600 + kcol;
    lA[it] = As + e*8;
    lB[it] = Bs + e*8;
  }

  floatx4 acc[4][4];
  #pragma unroll
  for (int i = 0; i < 4; i++)
    #pragma unroll
    for (int j = 0; j < 4; j++) acc[i][j] = (floatx4){0.f,0.f,0.f,0.f};

  for (int kc = 0; kc < 25; kc++) {
    #pragma unroll
    for (int it = 0; it < 4; it++) {
      gload_lds16(gA[it] + kc*64, lA[it]);
      gload_lds16(gB[it] + kc*64, lB[it]);
    }
    __syncthreads();
    #pragma unroll
    for (int ks = 0; ks < 2; ks++) {
      int colk = ((ks*4 + grp) ^ (l15 & 7)) * 8;   // un-swizzle at read
      short8 af[4], bf[4];
      #pragma unroll
      for (int i = 0; i < 4; i++) af[i] = *(const short8*)(As + (m0w + i*16 + l15)*64 + colk);
      #pragma unroll
      for (int j = 0; j < 4; j++) bf[j] = *(const short8*)(Bs + (c0w + j*16 + l15)*64 + colk);
      #pragma unroll
      for (int i = 0; i < 4; i++)
        #pragma unroll
        for (int j = 0; j < 4; j++)
          acc[i][j] = __builtin_amdgcn_mfma_f32_16x16x32_bf16(af[i], bf[j], acc[i][j], 0, 0, 0);
    }
    __syncthreads();
  }

  // epilogue: bias + relu -> yb bf16 (residual already inside U)
  #pragma unroll
  for (int i = 0; i < 4; i++) {
    int mbase = bm*128 + m0w + i*16 + grp*4;
    if (mbase >= 1600) continue;
    float4 bu = *(const float4*)(biasU + mbase);
    #pragma unroll
    for (int j = 0; j < 4; j++) {
      int col = c0w + j*16 + l15;
      int t = t0 + col;
      ushort4 pk;
      pk.x = f2us(fmaxf(acc[i][j][0] + bu.x, 0.f));
      pk.y = f2us(fmaxf(acc[i][j][1] + bu.y, 0.f));
      pk.z = f2us(fmaxf(acc[i][j][2] + bu.z, 0.f));
      pk.w = f2us(fmaxf(acc[i][j][3] + bu.w, 0.f));
      *(ushort4*)(yb + (long long)(n*256 + t)*1600 + mbase) = pk;
    }
  }
}

// ---------------- TCN as MFMA with im2col via LDS offsets ----------------
__global__ __launch_bounds__(256) void k_tcn(
    const unsigned short* yb, const unsigned short* cwetb, const float* cbe,
    fp x, float* out)
{
  int n = blockIdx.x >> 5, tb = blockIdx.x & 31, t0 = tb*8;
  int tid = threadIdx.x, lane = tid & 63, wid = tid >> 6;
  int l15 = lane & 15, grp = lane >> 4;
  __shared__ __align__(16) unsigned short ys[425*72];  // [17 t][25 v][72 i-pad]

  for (int e = tid; e < 3400; e += 256) {
    int row = e >> 3, li = e & 7;
    int rt = row / 25, v = row - rt*25;
    int tg = t0 - 4 + rt;
    uint4 val = {0u,0u,0u,0u};
    if (tg >= 0 && tg < 256)
      val = *(const uint4*)(yb + ((long long)(n*256 + tg)*1600 + v*64 + li*8));
    *(uint4*)(ys + row*72 + li*8) = val;
  }

  // A-frags: conv weights, o = o0+l15, k-dim = i
  int o0 = wid * 16;
  int o = o0 + l15;
  short8 af[9][2];
  #pragma unroll
  for (int j = 0; j < 9; j++) {
    af[j][0] = *(const short8*)(cwetb + ((o*9 + j)*64 + grp*8));
    af[j][1] = *(const short8*)(cwetb + ((o*9 + j)*64 + 32 + grp*8));
  }
  float4 cb4 = *(const float4*)(cbe + o0 + grp*4);
  __syncthreads();

  for (int tile = 0; tile < 13; tile++) {
    int colb = tile*16 + l15;
    int bbase = colb*72 + grp*8;
    floatx4 acc = (floatx4){0.f,0.f,0.f,0.f};
    #pragma unroll
    for (int j = 0; j < 9; j++) {
      short8 b0 = *(const short8*)(ys + bbase + j*1800);
      short8 b1 = *(const short8*)(ys + bbase + j*1800 + 32);
      acc = __builtin_amdgcn_mfma_f32_16x16x32_bf16(af[j][0], b0, acc, 0, 0, 0);
      acc = __builtin_amdgcn_mfma_f32_16x16x32_bf16(af[j][1], b1, acc, 0, 0, 0);
    }
    if (colb < 200) {
      int tt = colb / 25, v = colb - tt*25, t = t0 + tt;
      #pragma unroll
      for (int r = 0; r < 4; r++) {
        int oo = o0 + grp*4 + r;
        // residual read from fp32 x: lanes (l15) are contiguous in (t*25+v)
        float val = acc[r] + ((const float*)&cb4)[r]
                  + x[((n*64 + oo)*256 + t)*25 + v];
        out[((n*64 + oo)*256 + t)*25 + v] = fmaxf(val, 0.f);
      }
    }
  }
}

extern "C" void kernel_launch(void* const* d_in, const int* in_sizes, int n_in,
                              void* d_out, int out_size, void* d_ws, size_t ws_size,
                              hipStream_t stream)
{
  fp x  = (fp)d_in[0];
  fp A  = (fp)d_in[1];
  fp W  = (fp)d_in[2];
  fp b  = (fp)d_in[3];
  fp g0 = (fp)d_in[4];
  fp b0 = (fp)d_in[5];
  fp g1 = (fp)d_in[6];
  fp b1 = (fp)d_in[7];
  fp cw = (fp)d_in[8];
  fp cb = (fp)d_in[9];
  fp g2 = (fp)d_in[10];
  fp b2 = (fp)d_in[11];
  // d_in[12] = keep_prob == 1 -> DropBlocks identity.

  char* ws = (char*)d_ws;
  float*          normA = (float*)(ws + 0);
  float*          Weff  = (float*)(ws + 67584);
  float*          beff  = (float*)(ws + 116736);
  float*          cbe   = (float*)(ws + 117504);
  unsigned short* cwetb = (unsigned short*)(ws + 117760);
  float*          biasU = (float*)(ws + 191488);
  unsigned short* U     = (unsigned short*)(ws + 197888);
  unsigned short* xb    = (unsigned short*)(ws + 5522688);
  unsigned short* yb    = (unsigned short*)(ws + 31737088);

  k_pre<<<259, 256, 0, stream>>>(A, W, b, g0, b0, cw, cb, g2, b2,
                                 normA, Weff, beff, cbe, cwetb);
  k_pre2<<<10407, 256, 0, stream>>>(Weff, beff, normA, g1, b1, U, biasU);
  k_xt<<<25600, 256, 0, stream>>>(x, xb);
  k_gemm<<<832, 256, 0, stream>>>(U, xb, biasU, yb);
  k_tcn<<<1024, 256, 0, stream>>>(yb, cwetb, cbe, x, (float*)d_out);
}